// Round 11
// baseline (215.062 us; speedup 1.0000x reference)
//
#include <hip/hip_runtime.h>

typedef unsigned short u16;
typedef __bf16 bf16_t;
typedef bf16_t bf16x8 __attribute__((ext_vector_type(8)));
typedef float f32x4 __attribute__((ext_vector_type(4)));
typedef u16 u16x8 __attribute__((ext_vector_type(8)));

#define T_SZ 2048
#define EMB 1024

static __device__ __forceinline__ u16 f2bf(float f) {
  union { float f; unsigned u; } v; v.f = f;
  return (u16)((v.u + 0x7fffu + ((v.u >> 16) & 1u)) >> 16);  // RNE
}
// Packed f32x2 -> bf16x2 (single HW instruction).
static __device__ __forceinline__ unsigned cvtpk(float a, float b) {
  unsigned r;
  asm("v_cvt_pk_bf16_f32 %0, %1, %2" : "=v"(r) : "v"(a), "v"(b));
  return r;  // low 16 = bf16(a), high 16 = bf16(b)
}
static __device__ __forceinline__ void async16(const u16* g, u16* l) {
  typedef const __attribute__((address_space(1))) unsigned int* gp_t;
  typedef __attribute__((address_space(3))) unsigned int* lp_t;
  // LDS dest = wave-uniform base + lane*16.  Per-lane (even permuted) global
  // source addresses proven correct by the R4<->R7 absmax-identity oracle.
  __builtin_amdgcn_global_load_lds((gp_t)(const void*)g, (lp_t)(void*)l, 16, 0, 0);
}

// One fused fp32->bf16 convert for all 5 tensors (proven R6/R8).
__global__ __launch_bounds__(256) void cvt_all(
    const float* __restrict__ x,  const float* __restrict__ Wq,
    const float* __restrict__ Wk, const float* __restrict__ Wv,
    const float* __restrict__ Wp, u16* __restrict__ xb, u16* __restrict__ Wqb,
    u16* __restrict__ Wkb, u16* __restrict__ Wvb, u16* __restrict__ Wpb) {
  int bid = blockIdx.x;
  const float* src; u16* dst; int off;
  if (bid < 4096)      { src = x;  dst = xb;  off = bid * 2048; }
  else if (bid < 4608) { src = Wq; dst = Wqb; off = (bid - 4096) * 2048; }
  else if (bid < 4736) { src = Wk; dst = Wkb; off = (bid - 4608) * 2048; }
  else if (bid < 4864) { src = Wv; dst = Wvb; off = (bid - 4736) * 2048; }
  else                 { src = Wp; dst = Wpb; off = (bid - 4864) * 2048; }
  int i = off + threadIdx.x * 8;
  float4 a = *(const float4*)(src + i);
  float4 b = *(const float4*)(src + i + 4);
  u16x8 o;
  o[0] = f2bf(a.x); o[1] = f2bf(a.y); o[2] = f2bf(a.z); o[3] = f2bf(a.w);
  o[4] = f2bf(b.x); o[5] = f2bf(b.y); o[6] = f2bf(b.z); o[7] = f2bf(b.w);
  *(u16x8*)(dst + i) = o;
}

// GEMM body with XOR-swizzled gather staging (proven R8).
// MODE 0: bf16 [row][col] = f2bf(acc*cmul)        (Q/K outputs)
// MODE 1: f32  [row][col] = acc + bias             (final projection)
// MODE 2: bf16 V^T write: Vt[(b*4+g)*64+d][t], one ushort4 per (i,j)
//         (4 consecutive t per lane; replaces the transpose_v kernel with
//          16x8B stores vs the old 64x2B -- bit-identical values).
template <int MODE>
__device__ __forceinline__ void gemm_body(
    const u16* __restrict__ A, const u16* __restrict__ Bm,
    const float* __restrict__ bias, void* __restrict__ Cv,
    int N, int K, int tm, int tn, float cmul) {
  __shared__ u16 as[128 * 64];
  __shared__ u16 bs[128 * 64];
  const int tid = threadIdx.x;
  const int lane = tid & 63, wv = tid >> 6;
  const int quad = lane >> 4, l16 = lane & 15;
  const int wm = (wv & 1) * 64, wn = (wv >> 1) * 64;
  const int rA = lane >> 3;
  const int cS = ((lane & 7) ^ (rA & 7)) * 8;
  const int x7 = l16 & 7;
  f32x4 acc[4][4] = {};
  for (int k0 = 0; k0 < K; k0 += 64) {
#pragma unroll
    for (int it = 0; it < 4; ++it) {
      int r0 = it * 32 + wv * 8;
      async16(A + (size_t)(tm + r0 + rA) * K + k0 + cS, &as[r0 * 64]);
      async16(Bm + (size_t)(tn + r0 + rA) * K + k0 + cS, &bs[r0 * 64]);
    }
    __syncthreads();
#pragma unroll
    for (int kk = 0; kk < 64; kk += 32) {
      const int cb = kk >> 3;
      bf16x8 af[4], bfr[4];
#pragma unroll
      for (int i = 0; i < 4; ++i)
        af[i] = *(const bf16x8*)&as[(wm + i * 16 + l16) * 64 + (((cb + quad) ^ x7) * 8)];
#pragma unroll
      for (int j = 0; j < 4; ++j)
        bfr[j] = *(const bf16x8*)&bs[(wn + j * 16 + l16) * 64 + (((cb + quad) ^ x7) * 8)];
#pragma unroll
      for (int i = 0; i < 4; ++i)
#pragma unroll
        for (int j = 0; j < 4; ++j)
          acc[i][j] = __builtin_amdgcn_mfma_f32_16x16x32_bf16(af[i], bfr[j], acc[i][j], 0, 0, 0);
    }
    __syncthreads();
  }
#pragma unroll
  for (int i = 0; i < 4; ++i)
#pragma unroll
    for (int j = 0; j < 4; ++j) {
      int col = tn + wn + j * 16 + l16;
      if (MODE == 2) {
        // V^T: col = g*64+d (0..255), row block = b*2048+t, t = 4-aligned.
        int gg = col >> 6, d = col & 63;
        int rowg = tm + wm + i * 16 + quad * 4;
        int bb = rowg >> 11, t = rowg & 2047;
        ushort4 pk;
        pk.x = f2bf(acc[i][j][0]); pk.y = f2bf(acc[i][j][1]);
        pk.z = f2bf(acc[i][j][2]); pk.w = f2bf(acc[i][j][3]);
        *(ushort4*)((u16*)Cv + ((size_t)((bb * 4 + gg) * 64 + d)) * T_SZ + t) = pk;
      } else {
        float bv = (MODE == 1 && bias) ? bias[col] : 0.0f;
#pragma unroll
        for (int r = 0; r < 4; ++r) {
          int row = tm + wm + i * 16 + quad * 4 + r;
          if (MODE == 1)
            ((float*)Cv)[(size_t)row * N + col] = acc[i][j][r] + bv;
          else
            ((u16*)Cv)[(size_t)row * N + col] = f2bf(acc[i][j][r] * cmul);
        }
      }
    }
}

// Fused Q/K/V projection (proven R8).  Q pre-scaled by SCALE2; V written
// transposed directly (MODE 2) -- transpose_v kernel eliminated.
__global__ __launch_bounds__(256, 2) void gemm_qkv(
    const u16* __restrict__ x, const u16* __restrict__ Wq,
    const u16* __restrict__ Wk, const u16* __restrict__ Wv,
    u16* __restrict__ Qb, u16* __restrict__ Kb, u16* __restrict__ Vtb) {
  const int y = blockIdx.y;
  const float SCALE2 = 0.18033688011112042f;  // 0.125 * log2(e)
  if (y < 8) {
    gemm_body<0>(x, Wq, nullptr, Qb, 1024, 1024, blockIdx.x * 128, y * 128, SCALE2);
  } else if (y < 10) {
    gemm_body<0>(x, Wk, nullptr, Kb, 256, 1024, blockIdx.x * 128, (y - 8) * 128, 1.0f);
  } else {
    gemm_body<2>(x, Wv, nullptr, Vtb, 256, 1024, blockIdx.x * 128, (y - 10) * 128, 1.0f);
  }
}

// Output projection, fp32 out + bias (proven R8).
__global__ __launch_bounds__(256, 2) void gemm_out(
    const u16* __restrict__ A, const u16* __restrict__ Wp,
    const float* __restrict__ bias, float* __restrict__ C) {
  gemm_body<1>(A, Wp, bias, C, 1024, 1024, blockIdx.x * 128, blockIdx.y * 128, 1.0f);
}

// Flash attention, causal, GQA.  R19 = R16 verbatim (proven 72.0 us):
// pls exchange, fixed-max softmax, pre-scaled Q, diagonal-only mask,
// causal 2-pass pairing, XCD-L2 remap, depth-2 counted-vmcnt prefetch,
// setprio around MFMA clusters.
__global__ __launch_bounds__(512, 6) void gqa_attn(
    const u16* __restrict__ Q, const u16* __restrict__ Kg,
    const u16* __restrict__ Vt, u16* __restrict__ O) {
  __shared__ u16 kbuf[3][64 * 64];   // K-tile [kpos][d], swizzled
  __shared__ u16 vbuf[3][64 * 64];   // V^T-tile [d][kpos], swizzled
  __shared__ u16 pls[8][16 * 72];    // per-wave P [q][kpos], stride 72
  const int tid = threadIdx.x;
  const int lane = tid & 63, wv = tid >> 6;
  const int quad = lane >> 4, l16 = lane & 15;
  const int bid = blockIdx.x;
  const int xcd = bid & 7, slot = bid >> 3;
  const int pr = slot & 7, u2 = slot >> 3;
  const int bg = xcd + 8 * (u2 & 1);
  const int b = bg >> 2, g = bg & 3;
  const int h = g * 4 + (u2 >> 1);
  const size_t bT = (size_t)b * T_SZ;
  const int rA = lane >> 3;
  const int cS = ((lane & 7) ^ (rA & 7)) * 8;  // swizzled source chunk offset
  const int x7 = l16 & 7;
  const u16* vtb = Vt + (size_t)((b * 4 + g) * 64) * T_SZ;

#define STAGE(KT, BUF)                                                              \
  do {                                                                              \
    int kb_ = (KT) * 64, r0_ = wv * 8;  /* 8 waves x 8 rows = 64 */                 \
    async16(Kg + (bT + kb_ + r0_ + rA) * 256 + g * 64 + cS, &kbuf[BUF][r0_ * 64]);  \
    async16(vtb + (size_t)(r0_ + rA) * T_SZ + kb_ + cS, &vbuf[BUF][r0_ * 64]);      \
    __builtin_amdgcn_sched_barrier(0);                                              \
  } while (0)

  for (int pass = 0; pass < 2; ++pass) {
    const int qt = pass ? pr : 15 - pr;   // heavy strip first
    const int qstrip = qt * 128 + wv * 16;
    const int nkt = 2 * qt + 2;

    // Q B-fragment (n = q = l16, k = quad*8+j); already SCALE2-scaled.
    const u16* qp = Q + (bT + qstrip + l16) * EMB + h * 64 + quad * 8;
    const bf16x8 qf0 = *(const bf16x8*)qp;
    const bf16x8 qf1 = *(const bf16x8*)(qp + 32);

    f32x4 o[4] = {};                 // O^C: [q=quad*4+r][d=j*16+l16]
    float l_p = 0.0f;                // per-lane (quad-partial) running sum

    __syncthreads();                 // pass boundary: prior reads/stores drained
    STAGE(0, 0);
    STAGE(1, 1);
    for (int kt = 0; kt < nkt; ++kt) {
      // Counted drain: oldest in-flight stage (kt) must have landed; stage
      // kt+1 (2 loads/wave) may stay in flight across the barrier.
      if (kt < nkt - 1) { asm volatile("s_waitcnt vmcnt(2)" ::: "memory"); }
      else              { asm volatile("s_waitcnt vmcnt(0)" ::: "memory"); }
      __builtin_amdgcn_s_barrier();
      if (kt + 2 < nkt) STAGE(kt + 2, (kt + 2) % 3);
      const int cur = kt % 3;
      const int kb = kt * 64;
      const bool act = (kb <= qstrip + 15);  // wave-uniform

      if (act) {
        // S^T = K Q^T : s[jn][r] = S[kpos=kt*64+jn*16+quad*4+r][q=qstrip+l16]
        // (already in the scaled log2 domain -- Q was pre-scaled).
        f32x4 s4[4];
        __builtin_amdgcn_s_setprio(1);
#pragma unroll
        for (int jn = 0; jn < 4; ++jn) {
          const int rowb = (jn * 16 + l16) * 64;
          bf16x8 kf0 = *(const bf16x8*)&kbuf[cur][rowb + ((quad ^ x7) * 8)];
          bf16x8 kf1 = *(const bf16x8*)&kbuf[cur][rowb + (((4 + quad) ^ x7) * 8)];
          f32x4 a = {};
          a = __builtin_amdgcn_mfma_f32_16x16x32_bf16(kf0, qf0, a, 0, 0, 0);
          a = __builtin_amdgcn_mfma_f32_16x16x32_bf16(kf1, qf1, a, 0, 0, 0);
          s4[jn] = a;
        }
        __builtin_amdgcn_s_setprio(0);
        // Causal mask: needed only on the single diagonal tile of this wave.
        if (kb + 63 > qstrip) {
          const int qg = qstrip + l16;
#pragma unroll
          for (int jn = 0; jn < 4; ++jn)
#pragma unroll
            for (int r = 0; r < 4; ++r)
              if (kb + jn * 16 + quad * 4 + r > qg) s4[jn][r] = -1e30f;
        }
        // Fixed-max softmax: p = exp2(s2) (exp2(-1e30) = 0 for masked).
        float sj[4];
#pragma unroll
        for (int jn = 0; jn < 4; ++jn) {
#pragma unroll
          for (int r = 0; r < 4; ++r) s4[jn][r] = exp2f(s4[jn][r]);
          sj[jn] = (s4[jn][0] + s4[jn][1]) + (s4[jn][2] + s4[jn][3]);
        }
        l_p += (sj[0] + sj[1]) + (sj[2] + sj[3]);
        // P store: packed cvt, 4 consecutive kpos per lane -> ds_write_b64.
#pragma unroll
        for (int jn = 0; jn < 4; ++jn) {
          uint2 w;
          w.x = cvtpk(s4[jn][0], s4[jn][1]);
          w.y = cvtpk(s4[jn][2], s4[jn][3]);
          *(uint2*)&pls[wv][l16 * 72 + jn * 16 + quad * 4] = w;
        }
        // PV: per-wave P round-trip ordered by lgkmcnt (no barrier needed).
        bf16x8 pf0 = *(const bf16x8*)&pls[wv][l16 * 72 + quad * 8];
        bf16x8 pf1 = *(const bf16x8*)&pls[wv][l16 * 72 + 32 + quad * 8];
        __builtin_amdgcn_s_setprio(1);
#pragma unroll
        for (int j = 0; j < 4; ++j) {
          const int rowb = (j * 16 + l16) * 64;
          bf16x8 vf0 = *(const bf16x8*)&vbuf[cur][rowb + ((quad ^ x7) * 8)];
          bf16x8 vf1 = *(const bf16x8*)&vbuf[cur][rowb + (((4 + quad) ^ x7) * 8)];
          o[j] = __builtin_amdgcn_mfma_f32_16x16x32_bf16(pf0, vf0, o[j], 0, 0, 0);
          o[j] = __builtin_amdgcn_mfma_f32_16x16x32_bf16(pf1, vf1, o[j], 0, 0, 0);
        }
        __builtin_amdgcn_s_setprio(0);
      }
    }
    // Cross-quad row-sum reduce, normalize + write.
    float l_l = l_p;
    l_l += __shfl_xor(l_l, 16);
    l_l += __shfl_xor(l_l, 32);
#pragma unroll
    for (int r = 0; r < 4; ++r) {
      float inv = 1.0f / __shfl(l_l, quad * 4 + r, 16);
      int row = qstrip + quad * 4 + r;
#pragma unroll
      for (int j = 0; j < 4; ++j)
        O[(bT + row) * EMB + h * 64 + j * 16 + l16] = f2bf(o[j][r] * inv);
    }
  }
#undef STAGE
}

extern "C" void kernel_launch(void* const* d_in, const int* in_sizes, int n_in,
                              void* d_out, int out_size, void* d_ws, size_t ws_size,
                              hipStream_t stream) {
  const float* x  = (const float*)d_in[0];
  const float* Wq = (const float*)d_in[1];
  const float* Wk = (const float*)d_in[2];
  const float* Wv = (const float*)d_in[3];
  const float* Wp = (const float*)d_in[4];
  const float* bp = (const float*)d_in[5];
  float* out = (float*)d_out;

  u16* ws = (u16*)d_ws;
  u16* Qb  = ws;                              // 8M u16
  u16* Kb  = Qb + (size_t)8192 * 1024;        // 2M
  u16* Vb  = Kb + (size_t)8192 * 256;         // 2M (unused; kept for layout)
  u16* Vtb = Vb + (size_t)8192 * 256;         // 2M
  u16* xb  = Vtb + (size_t)8192 * 256;        // 8M (reused as Ab after QKV)
  u16* Wqb = xb + (size_t)8192 * 1024;        // 1M
  u16* Wkb = Wqb + (size_t)1024 * 1024;       // 256K
  u16* Wvb = Wkb + (size_t)256 * 1024;        // 256K
  u16* Wpb = Wvb + (size_t)256 * 1024;        // 1M  -> 24.5M u16 = 49 MB
  u16* Ab  = xb;                              // alias: x dead after QKV GEMM

  cvt_all<<<dim3(5376), 256, 0, stream>>>(x, Wq, Wk, Wv, Wp, xb, Wqb, Wkb, Wvb, Wpb);
  gemm_qkv<<<dim3(64, 12), 256, 0, stream>>>(xb, Wqb, Wkb, Wvb, Qb, Kb, Vtb);
  gqa_attn<<<dim3(512), 512, 0, stream>>>(Qb, Kb, Vtb, Ab);
  gemm_out<<<dim3(64, 8), 256, 0, stream>>>(Ab, Wpb, bp, out);
}